// Round 2
// baseline (103.045 us; speedup 1.0000x reference)
//
#include <hip/hip_runtime.h>

#define L 4096
#define NT 256
#define PER (L / NT)        // 16 elements per thread
#define MD 32               // MIN_DIST
#define ML (MD + L)         // doubling domain: conceptual positions [-32, L)
#define STASH 17            // ceil(ML / NT)

// One block per row. Exact greedy NMS via iterative local-max peeling.
// Composite key (distinct across i): (valid<<44) | (bits(|x|)<<12) | (4095-i)
// so descending-key order == JAX stable argsort(-|x|) order.
__global__ __launch_bounds__(NT) void extrema_nms_kernel(const float* __restrict__ in,
                                                         float* __restrict__ out) {
    __shared__ float xs[L];
    __shared__ unsigned long long K[L + MD];                 // tail pad (zeros) for K[i+32]
    __shared__ unsigned long long Mfull[MD + L + MD];        // [0,MD)=front pad, tail pad zeros
    __shared__ unsigned long long keptbits[L / 64];
    __shared__ int sAny;

    const int tid = threadIdx.x;
    const int row = blockIdx.x;
    const float* x = in + (size_t)row * L;

    // ---- load row + zero pads/flags ----
    #pragma unroll
    for (int k = 0; k < PER; ++k) xs[tid + k * NT] = x[tid + k * NT];
    if (tid < MD) {
        K[L + tid] = 0ULL;                // K tail pad
        Mfull[MD + L + tid] = 0ULL;       // M tail pad (never written again)
    }
    if (tid < L / 64) keptbits[tid] = 0ULL;
    if (tid == 0) sAny = 0;
    __syncthreads();

    // ---- extrema mask -> sortable composite key ----
    // right[i] = (i<L-1) && x[i+1] >  x[i]   (end pad => False at L-1)
    // left[i]  = (i==0)  || x[i]   <= x[i-1] (front pad => True at 0)
    // valley = right & left & (x<=0) ; peak = !right & !left & (x>0)
    #pragma unroll
    for (int k = 0; k < PER; ++k) {
        int i = tid + k * NT;
        float xi = xs[i];
        bool right = (i < L - 1) && (xs[i + 1] > xi);
        bool left  = (i == 0) || (xi <= xs[i - 1]);
        bool neg   = (xi <= 0.0f);
        bool valley = right && left && neg;
        bool peak   = (!right) && (!left) && (!neg);
        unsigned long long key = 0ULL;
        if (valley || peak) {
            unsigned int ab = __float_as_uint(xi) & 0x7fffffffu;
            key = (1ULL << 44) | ((unsigned long long)ab << 12)
                | (unsigned long long)(L - 1 - i);
        }
        K[i] = key;
    }
    __syncthreads();

    // ---- peeling rounds (exact greedy NMS fixpoint) ----
    for (int round = 0; round < 300; ++round) {
        // init M: front pad = 0 (re-zero each round; doubling overwrites it),
        //         M[MD+i] = K[i]
        if (tid < MD) Mfull[tid] = 0ULL;
        #pragma unroll
        for (int k = 0; k < PER; ++k) Mfull[MD + tid + k * NT] = K[tid + k * NT];
        __syncthreads();

        // in-place doubling over [0, ML): after step d, Mfull[m] = max over
        // conceptual positions [m-MD, m-MD+2d-1] (clipped; pads supply zeros)
        for (int d = 1; d <= MD; d <<= 1) {
            unsigned long long a[STASH];
            int cnt = 0;
            for (int m = tid; m < ML; m += NT) {
                unsigned long long m0 = Mfull[m];
                unsigned long long m1 = Mfull[m + d];
                a[cnt++] = (m0 > m1) ? m0 : m1;
            }
            __syncthreads();
            cnt = 0;
            for (int m = tid; m < ML; m += NT) Mfull[m] = a[cnt++];
            __syncthreads();
        }
        // now Mfull[i] = max K over [i-32, i+31] (clipped), for i in [0, L)

        // winner: active and strict max over window [i-32, i+32]
        int winIdx[PER];
        int nWin = 0;
        #pragma unroll
        for (int k = 0; k < PER; ++k) {
            int i = tid + k * NT;
            unsigned long long Ki = K[i];
            if (Ki) {
                unsigned long long W = Mfull[i];       // max over [i-32, i+31]
                unsigned long long Kr = K[i + MD];     // the 65th element
                if (Kr > W) W = Kr;
                if (W == Ki) winIdx[nWin++] = i;       // unique max (keys distinct)
            }
        }
        if (nWin) sAny = 1;                            // benign same-value race
        __syncthreads();                               // (B) detection reads done
        int go = sAny;
        __syncthreads();                               // (C) everyone read sAny
        if (tid == 0) sAny = 0;
        if (!go) break;                                // uniform across block

        // deactivate windows + record kept
        for (int w = 0; w < nWin; ++w) {
            int i = winIdx[w];
            atomicOr(&keptbits[i >> 6], 1ULL << (i & 63));
            int lo = i - MD; if (lo < 0) lo = 0;
            int hi = i + MD; if (hi > L - 1) hi = L - 1;
            for (int j = lo; j <= hi; ++j) K[j] = 0ULL; // same-value races benign
        }
        __syncthreads();                               // (A) K stable for next round
    }
    __syncthreads();

    // ---- output ----
    #pragma unroll
    for (int k = 0; k < PER; ++k) {
        int i = tid + k * NT;
        bool kept = (keptbits[i >> 6] >> (i & 63)) & 1ULL;
        out[(size_t)row * L + i] = kept ? xs[i] : 0.0f;
    }
}

extern "C" void kernel_launch(void* const* d_in, const int* in_sizes, int n_in,
                              void* d_out, int out_size, void* d_ws, size_t ws_size,
                              hipStream_t stream) {
    const float* in = (const float*)d_in[0];
    float* out = (float*)d_out;
    int rows = in_sizes[0] / L;   // 128
    extrema_nms_kernel<<<rows, NT, 0, stream>>>(in, out);
}